// Round 6
// baseline (510.499 us; speedup 1.0000x reference)
//
#include <hip/hip_runtime.h>

#define TPB 256
#define NBMAX 128     // coarse buckets (dst>>10), N <= 131072
#define BCAP 18432    // per-bucket pair capacity: mean 16384 + ~16 sigma
#define BK_TILE 2048  // edges per bucket_kernel block (256 thr x 8)

typedef float f32x4 __attribute__((ext_vector_type(4)));

// ================= Phase A: coarse bucket by dst>>10, coalesced appends ========

__global__ void bucket_kernel(const int* __restrict__ ei, int* __restrict__ bcnt,
                              int2* __restrict__ pairs, int E, int nbk) {
    __shared__ int hcnt[NBMAX], hoff[NBMAX], hcur[NBMAX], gbase[NBMAX];
    __shared__ int2 stage[BK_TILE];
    __shared__ int stot;
    for (int i = threadIdx.x; i < NBMAX; i += TPB) hcnt[i] = 0;
    __syncthreads();
    int base = blockIdx.x * BK_TILE;
    int src[8], dst[8], bb[8];
#pragma unroll
    for (int i = 0; i < 8; ++i) {
        int e = base + i * TPB + threadIdx.x;
        bool ok = e < E;
        src[i] = ok ? ei[e] : 0;
        dst[i] = ok ? ei[E + e] : 0;
        bb[i]  = ok ? (dst[i] >> 10) : -1;
        if (ok) atomicAdd(&hcnt[bb[i]], 1);
    }
    __syncthreads();
    if (threadIdx.x == 0) {
        int run = 0;
        for (int b = 0; b < nbk; ++b) { hoff[b] = run; run += hcnt[b]; }
        stot = run;
    }
    __syncthreads();
    for (int i = threadIdx.x; i < NBMAX; i += TPB) hcur[i] = hoff[i];
    __syncthreads();
#pragma unroll
    for (int i = 0; i < 8; ++i) {
        if (bb[i] >= 0) {
            int r = atomicAdd(&hcur[bb[i]], 1);
            stage[r] = make_int2(src[i], dst[i]);
        }
    }
    __syncthreads();
    if (threadIdx.x < nbk)
        gbase[threadIdx.x] = atomicAdd(&bcnt[threadIdx.x], hcnt[threadIdx.x]);
    __syncthreads();
    int tot = stot;
    for (int t = threadIdx.x; t < tot; t += TPB) {
        int2 p = stage[t];
        int b = p.y >> 10;
        int gpos = gbase[b] + (t - hoff[b]);
        if (gpos < BCAP) pairs[(size_t)b * BCAP + gpos] = p;   // coalesced runs
    }
}

// ============ tiny scan: bstart[b] = prefix of clamped bcnt =====

__global__ void bstart_kernel(const int* __restrict__ bcnt, int* __restrict__ bstart, int nbk) {
    __shared__ int wtot[4];
    int i = threadIdx.x;
    int v = (i < nbk) ? min(bcnt[i], BCAP) : 0;
    int lane = i & 63, w = i >> 6;
    int inc = v;
    for (int off = 1; off < 64; off <<= 1) {
        int u = __shfl_up(inc, off);
        if (lane >= off) inc += u;
    }
    if (lane == 63) wtot[w] = inc;
    __syncthreads();
    int woff = 0;
    for (int k = 0; k < w; ++k) woff += wtot[k];
    int excl = woff + inc - v;
    if (i <= nbk) bstart[i] = excl;
}

// ===== Phase B: per-bucket counting sort in LDS -> rowptr, dinv, coalesced csr =====

__global__ void __launch_bounds__(TPB)
fill3_kernel(const int2* __restrict__ pairs, const int* __restrict__ bcnt,
             const int* __restrict__ bstart, int* __restrict__ rowptr,
             float* __restrict__ dinv, int* __restrict__ csr, int N) {
    __shared__ int h[1024];
    __shared__ int wtot[4];
    __shared__ int sbuf[BCAP];
    int b = blockIdx.x;
    int sz = min(bcnt[b], BCAP);
    int base = b << 10;
    int gbase = bstart[b];
    const int2* pb = pairs + (size_t)b * BCAP;

    for (int i = threadIdx.x; i < 1024; i += TPB) h[i] = 0;
    __syncthreads();
    for (int t = threadIdx.x; t < sz; t += TPB)
        atomicAdd(&h[pb[t].y - base], 1);
    __syncthreads();
    int t4 = threadIdx.x * 4;
    int v0 = h[t4], v1 = h[t4 + 1], v2 = h[t4 + 2], v3 = h[t4 + 3];
    int s = v0 + v1 + v2 + v3;
    int lane = threadIdx.x & 63, w = threadIdx.x >> 6;
    int inc = s;
    for (int off = 1; off < 64; off <<= 1) {
        int u = __shfl_up(inc, off);
        if (lane >= off) inc += u;
    }
    if (lane == 63) wtot[w] = inc;
    __syncthreads();
    int woff = 0;
    for (int k = 0; k < w; ++k) woff += wtot[k];
    int excl = woff + inc - s;
    int o0 = excl, o1 = excl + v0, o2 = excl + v0 + v1, o3 = excl + v0 + v1 + v2;
    h[t4] = o0; h[t4 + 1] = o1; h[t4 + 2] = o2; h[t4 + 3] = o3;
    int offs[4] = {o0, o1, o2, o3};
    int degs[4] = {v0, v1, v2, v3};
#pragma unroll
    for (int j = 0; j < 4; ++j) {
        int idx = base + t4 + j;
        if (idx <= N) rowptr[idx] = gbase + offs[j];
        if (idx <  N) dinv[idx] = rsqrtf((float)degs[j] + 1.0f);
    }
    __syncthreads();
    for (int t = threadIdx.x; t < sz; t += TPB) {
        int2 p = pb[t];
        int r = atomicAdd(&h[p.y - base], 1);
        sbuf[r] = p.x;
    }
    __syncthreads();
    for (int t = threadIdx.x; t < sz; t += TPB)
        csr[gbase + t] = sbuf[t];
}

// ========== first-layer dense linear (row-major out) ==========

template<int DIN, int ISTR, int DOUT, int OSTR, bool RELU, bool SCALE>
__global__ void __launch_bounds__(TPB)
linear_kernel(const float* __restrict__ x, const float* __restrict__ W,
              const float* __restrict__ b, const float* __restrict__ dinv,
              float* __restrict__ y, int n) {
    __shared__ float sW[DIN * DOUT];
    __shared__ float sb[DOUT];
    for (int i = threadIdx.x; i < DIN * DOUT; i += blockDim.x) sW[i] = W[i];
    for (int i = threadIdx.x; i < DOUT; i += blockDim.x) sb[i] = b ? b[i] : 0.0f;
    __syncthreads();
    int row = blockIdx.x * blockDim.x + threadIdx.x;
    if (row >= n) return;
    float acc[DOUT];
#pragma unroll
    for (int j = 0; j < DOUT; ++j) acc[j] = sb[j];
    const float* xr = x + (size_t)row * ISTR;
    if constexpr (DIN % 4 == 0 && ISTR % 4 == 0) {
        const float4* xr4 = (const float4*)xr;
#pragma unroll
        for (int k4 = 0; k4 < DIN / 4; ++k4) {
            float4 xv = xr4[k4];
#pragma unroll
            for (int j = 0; j < DOUT; ++j) acc[j] = fmaf(xv.x, sW[(k4 * 4 + 0) * DOUT + j], acc[j]);
#pragma unroll
            for (int j = 0; j < DOUT; ++j) acc[j] = fmaf(xv.y, sW[(k4 * 4 + 1) * DOUT + j], acc[j]);
#pragma unroll
            for (int j = 0; j < DOUT; ++j) acc[j] = fmaf(xv.z, sW[(k4 * 4 + 2) * DOUT + j], acc[j]);
#pragma unroll
            for (int j = 0; j < DOUT; ++j) acc[j] = fmaf(xv.w, sW[(k4 * 4 + 3) * DOUT + j], acc[j]);
        }
    } else {
#pragma unroll
        for (int k = 0; k < DIN; ++k) {
            float xv = xr[k];
#pragma unroll
            for (int j = 0; j < DOUT; ++j) acc[j] = fmaf(xv, sW[k * DOUT + j], acc[j]);
        }
    }
    float sc = SCALE ? dinv[row] : 1.0f;
    float* yr = y + (size_t)row * OSTR;
#pragma unroll
    for (int j = 0; j < DOUT; ++j) {
        float v = RELU ? fmaxf(acc[j], 0.0f) : acc[j];
        yr[j] = SCALE ? v * sc : v;
    }
#pragma unroll
    for (int j = DOUT; j < OSTR; ++j) yr[j] = 0.0f;
}

// ========== conv linear: xw_chunked[c][row][0..7] = dinv[row] * (x @ W) ==========
// Output chunk-major [PAD/8][n][8] so each 8-dim chunk is a contiguous 3.2MB
// array that fits in one XCD's 4MB L2 during the gather.

template<int DIN, int DOUT, int PAD>
__global__ void __launch_bounds__(TPB)
linear_chunk_kernel(const float* __restrict__ x, const float* __restrict__ W,
                    const float* __restrict__ dinv, f32x4* __restrict__ xw, int n) {
    __shared__ float sW[DIN * DOUT];
    for (int i = threadIdx.x; i < DIN * DOUT; i += blockDim.x) sW[i] = W[i];
    __syncthreads();
    int row = blockIdx.x * blockDim.x + threadIdx.x;
    if (row >= n) return;
    float acc[DOUT];
#pragma unroll
    for (int j = 0; j < DOUT; ++j) acc[j] = 0.0f;
    const float4* xr4 = (const float4*)(x + (size_t)row * DIN);
#pragma unroll
    for (int k4 = 0; k4 < DIN / 4; ++k4) {
        float4 xv = xr4[k4];
#pragma unroll
        for (int j = 0; j < DOUT; ++j) acc[j] = fmaf(xv.x, sW[(k4 * 4 + 0) * DOUT + j], acc[j]);
#pragma unroll
        for (int j = 0; j < DOUT; ++j) acc[j] = fmaf(xv.y, sW[(k4 * 4 + 1) * DOUT + j], acc[j]);
#pragma unroll
        for (int j = 0; j < DOUT; ++j) acc[j] = fmaf(xv.z, sW[(k4 * 4 + 2) * DOUT + j], acc[j]);
#pragma unroll
        for (int j = 0; j < DOUT; ++j) acc[j] = fmaf(xv.w, sW[(k4 * 4 + 3) * DOUT + j], acc[j]);
    }
    float sc = dinv[row];
    constexpr int C = PAD / 8;
#pragma unroll
    for (int c = 0; c < C; ++c) {
        f32x4 w0, w1;
#pragma unroll
        for (int j = 0; j < 4; ++j) {
            int d = c * 8 + j;
            w0[j] = (d < DOUT) ? sc * acc[d] : 0.0f;
        }
#pragma unroll
        for (int j = 0; j < 4; ++j) {
            int d = c * 8 + 4 + j;
            w1[j] = (d < DOUT) ? sc * acc[d] : 0.0f;
        }
        xw[((size_t)c * n + row) * 2 + 0] = w0;
        xw[((size_t)c * n + row) * 2 + 1] = w1;
    }
}

// ========== chunked GCN gather, XCD-spatial chunk mapping ==========
// NCHUNK chunks handled; chunk = (blockIdx&7)*NCHUNK/8, so each XCD only ever
// reads ONE 3.2MB chunk -> L2-resident after compulsory fill. d0base offsets
// the output dims (tail kernels). y written row-major stride OSTR (nt store).

template<int NCHUNK, int OSTR, int DOUT, bool RELU>
__global__ void __launch_bounds__(TPB)
gather_chunk_kernel(const int* __restrict__ rowptr, const int* __restrict__ csr,
                    const f32x4* __restrict__ xw, const float* __restrict__ dinv,
                    const float* __restrict__ bias, float* __restrict__ y,
                    int n, int d0base) {
    constexpr int G = 8 / NCHUNK;        // XCDs per chunk
    int x = blockIdx.x & 7;
    int c = x / G;
    int wid = (blockIdx.x >> 3) * G + (x - c * G);
    int t = wid * TPB + (int)threadIdx.x;
    if (t >= 2 * n) return;
    int v = t >> 1, q = t & 1;
    const f32x4* base = xw + (size_t)c * ((size_t)2 * n);
    f32x4 acc = base[(size_t)2 * v + q];          // self-loop term
    int k = rowptr[v], end = rowptr[v + 1];
    if (k < end) {
        int src = csr[k];
        for (++k; k < end; ++k) {
            int ns = csr[k];                      // prefetch next index
            acc += base[(size_t)2 * src + q];
            src = ns;
        }
        acc += base[(size_t)2 * src + q];
    }
    float di = dinv[v];
    int d0 = d0base + c * 8 + q * 4;
    f32x4 bv;
#pragma unroll
    for (int j = 0; j < 4; ++j) bv[j] = (d0 + j < DOUT) ? bias[d0 + j] : 0.0f;
    f32x4 r = acc * di + bv;
    if (RELU) {
#pragma unroll
        for (int j = 0; j < 4; ++j) r[j] = fmaxf(r[j], 0.0f);
    }
    if (d0 < OSTR)
        __builtin_nontemporal_store(r, (f32x4*)(y + (size_t)v * OSTR + d0));
}

// ========== head (xf stride 36, xs stride 12) ==========

__global__ void __launch_bounds__(TPB)
head_kernel(const float* __restrict__ xf, const float* __restrict__ xs,
            const float* __restrict__ W1, const float* __restrict__ b1,
            const float* __restrict__ W2, const float* __restrict__ b2,
            float* __restrict__ out, int n) {
    __shared__ float sW1[44 * 33];
    __shared__ float sW2[33 * 30];
    __shared__ float sb1[33];
    __shared__ float sb2[30];
    for (int i = threadIdx.x; i < 44 * 33; i += blockDim.x) sW1[i] = W1[i];
    for (int i = threadIdx.x; i < 33 * 30; i += blockDim.x) sW2[i] = W2[i];
    for (int i = threadIdx.x; i < 33; i += blockDim.x) sb1[i] = b1[i];
    for (int i = threadIdx.x; i < 30; i += blockDim.x) sb2[i] = b2[i];
    __syncthreads();
    int row = blockIdx.x * blockDim.x + threadIdx.x;
    if (row >= n) return;
    float xv[44];
    const float* xfr = xf + (size_t)row * 36;
    const float* xsr = xs + (size_t)row * 12;
#pragma unroll
    for (int k = 0; k < 33; ++k) xv[k] = fmaxf(xfr[k], 0.0f);
#pragma unroll
    for (int k = 0; k < 11; ++k) xv[33 + k] = fmaxf(xsr[k], 0.0f);
    float h[33];
#pragma unroll
    for (int j = 0; j < 33; ++j) h[j] = sb1[j];
#pragma unroll
    for (int k = 0; k < 44; ++k) {
        float xk = xv[k];
#pragma unroll
        for (int j = 0; j < 33; ++j) h[j] = fmaf(xk, sW1[k * 33 + j], h[j]);
    }
    float o[30];
#pragma unroll
    for (int j = 0; j < 30; ++j) o[j] = sb2[j];
#pragma unroll
    for (int k = 0; k < 33; ++k) {
        float hk = fmaxf(h[k], 0.0f);
#pragma unroll
        for (int j = 0; j < 30; ++j) o[j] = fmaf(hk, sW2[k * 30 + j], o[j]);
    }
    float* orow = out + (size_t)row * 30;
#pragma unroll
    for (int j = 0; j < 30; ++j) orow[j] = o[j];
}

// ================= launch =================

extern "C" void kernel_launch(void* const* d_in, const int* in_sizes, int n_in,
                              void* d_out, int out_size, void* d_ws, size_t ws_size,
                              hipStream_t stream) {
    const float* feat  = (const float*)d_in[0];
    const float* spat  = (const float*)d_in[1];
    const int*   ei_f  = (const int*)d_in[2];
    const int*   ei_s  = (const int*)d_in[3];
    const float* W_fc  = (const float*)d_in[4];
    const float* b_fc  = (const float*)d_in[5];
    const float* W_cnn = (const float*)d_in[6];
    const float* b_cnn = (const float*)d_in[7];
    const float* Wf1 = (const float*)d_in[8];
    const float* bf1 = (const float*)d_in[9];
    const float* Wf2 = (const float*)d_in[10];
    const float* bf2 = (const float*)d_in[11];
    const float* Ws1 = (const float*)d_in[12];
    const float* bs1 = (const float*)d_in[13];
    const float* Ws2 = (const float*)d_in[14];
    const float* bs2 = (const float*)d_in[15];
    const float* Wp1 = (const float*)d_in[16];
    const float* bp1 = (const float*)d_in[17];
    const float* Wp2 = (const float*)d_in[18];
    const float* bp2 = (const float*)d_in[19];
    float* out = (float*)d_out;

    const int N = in_sizes[0] / 31;
    const int E = in_sizes[2] / 2;
    const int nbk = (N + 1023) / 1024;
    const int bgrid = (E + BK_TILE - 1) / BK_TILE;

    // workspace layout (4B elements), ~55MB
    float* R0   = (float*)d_ws;                  // N*36 row-major ping
    float* R1   = R0 + (size_t)N * 36;           // N*32 row-major pong
    float* XW   = R1 + (size_t)N * 32;           // N*40 chunk-major
    float* S    = XW + (size_t)N * 40;           // N*12 (xs2)
    float* dinv = S + (size_t)N * 12;            // N
    int*   rowptr = (int*)(dinv + N);            // N+1
    int*   bcnt   = rowptr + (N + 1);            // 128
    int*   bstart = bcnt + 128;                  // 129
    int*   csr    = bstart + 132;                // E
    int2*  pairs  = (int2*)R0;                   // 128*BCAP int2 = 18.9MB, overlays R0∪R1 (dead during builds)

    auto gb = [](long long n) { return (unsigned)((n + TPB - 1) / TPB); };
    const int wpc = (2 * N + TPB - 1) / TPB;          // wave-groups per chunk
    const unsigned grid4 = (unsigned)((wpc + 1) / 2) * 8;   // NCHUNK=4 (2 XCDs/chunk)
    const unsigned grid2 = (unsigned)((wpc + 3) / 4) * 8;   // NCHUNK=2 (4 XCDs/chunk)
    const unsigned grid1 = (unsigned)((wpc + 7) / 8) * 8;   // NCHUNK=1 (8 XCDs)

    // ---------- spat CSR + branch (first, so only small S survives) ----------
    hipMemsetAsync(bcnt, 0, sizeof(int) * NBMAX, stream);
    bucket_kernel<<<bgrid, TPB, 0, stream>>>(ei_s, bcnt, pairs, E, nbk);
    bstart_kernel<<<1, TPB, 0, stream>>>(bcnt, bstart, nbk);
    fill3_kernel<<<nbk, TPB, 0, stream>>>(pairs, bcnt, bstart, rowptr, dinv, csr, N);

    linear_kernel<128, 128, 32, 32, true, false><<<gb(N), TPB, 0, stream>>>(spat, W_cnn, b_cnn, nullptr, R0, N);
    linear_chunk_kernel<32, 32, 32><<<gb(N), TPB, 0, stream>>>(R0, Ws1, dinv, (f32x4*)XW, N);
    gather_chunk_kernel<4, 32, 32, true><<<grid4, TPB, 0, stream>>>(rowptr, csr, (const f32x4*)XW, dinv, bs1, R1, N, 0);
    linear_chunk_kernel<32, 11, 16><<<gb(N), TPB, 0, stream>>>(R1, Ws2, dinv, (f32x4*)XW, N);
    gather_chunk_kernel<2, 12, 11, false><<<grid2, TPB, 0, stream>>>(rowptr, csr, (const f32x4*)XW, dinv, bs2, S, N, 0);
    // xs2 -> S (stride 12)

    // ---------- feat CSR + branch ----------
    hipMemsetAsync(bcnt, 0, sizeof(int) * NBMAX, stream);
    bucket_kernel<<<bgrid, TPB, 0, stream>>>(ei_f, bcnt, pairs, E, nbk);
    bstart_kernel<<<1, TPB, 0, stream>>>(bcnt, bstart, nbk);
    fill3_kernel<<<nbk, TPB, 0, stream>>>(pairs, bcnt, bstart, rowptr, dinv, csr, N);

    linear_kernel<31, 31, 32, 32, true, false><<<gb(N), TPB, 0, stream>>>(feat, W_fc, b_fc, nullptr, R0, N);
    linear_chunk_kernel<32, 32, 32><<<gb(N), TPB, 0, stream>>>(R0, Wf1, dinv, (f32x4*)XW, N);
    gather_chunk_kernel<4, 32, 32, true><<<grid4, TPB, 0, stream>>>(rowptr, csr, (const f32x4*)XW, dinv, bf1, R1, N, 0);
    linear_chunk_kernel<32, 33, 40><<<gb(N), TPB, 0, stream>>>(R1, Wf2, dinv, (f32x4*)XW, N);
    gather_chunk_kernel<4, 36, 33, false><<<grid4, TPB, 0, stream>>>(rowptr, csr, (const f32x4*)XW, dinv, bf2, R0, N, 0);
    gather_chunk_kernel<1, 36, 33, false><<<grid1, TPB, 0, stream>>>(rowptr, csr, (const f32x4*)XW + (size_t)4 * 2 * N, dinv, bf2, R0, N, 32);
    // xf2 -> R0 (stride 36)

    // ---------- head ----------
    head_kernel<<<gb(N), TPB, 0, stream>>>(R0, S, Wp1, bp1, Wp2, bp2, out, N);
}

// Round 7
// 376.624 us; speedup vs baseline: 1.3555x; 1.3555x over previous
//
#include <hip/hip_runtime.h>
#include <hip/hip_fp16.h>

#define TPB 256
#define RSH 8         // bucket = dst >> 8 (256 dsts per bucket)
#define NBMAX 512     // max buckets (N <= 131072)
#define BCAP 5120     // per-bucket pair capacity: mean 4096 + 16 sigma
#define BK_TILE 2048  // edges per bucket_kernel block (256 thr x 8)

// ================= Phase A: coarse bucket by dst>>8, coalesced appends ========

__global__ void __launch_bounds__(TPB)
bucket_kernel(const int* __restrict__ ei, int* __restrict__ bcnt,
              int2* __restrict__ pairs, int E, int nbk) {
    __shared__ int hcnt[NBMAX], hoff[NBMAX], hcur[NBMAX], gbase[NBMAX];
    __shared__ int wtot[4];
    __shared__ int2 stage[BK_TILE];
    int i0 = threadIdx.x * 2;
    hcnt[i0] = 0; hcnt[i0 + 1] = 0;
    __syncthreads();
    int base = blockIdx.x * BK_TILE;
    int src[8], dst[8], bb[8];
#pragma unroll
    for (int i = 0; i < 8; ++i) {
        int e = base + i * TPB + threadIdx.x;
        bool ok = e < E;
        src[i] = ok ? ei[e] : 0;
        dst[i] = ok ? ei[E + e] : 0;
        bb[i]  = ok ? (dst[i] >> RSH) : -1;
        if (ok) atomicAdd(&hcnt[bb[i]], 1);
    }
    __syncthreads();
    // parallel exclusive scan over bins, 2 per thread
    int v0 = hcnt[i0], v1 = hcnt[i0 + 1];
    int s = v0 + v1;
    int lane = threadIdx.x & 63, w = threadIdx.x >> 6;
    int inc = s;
    for (int off = 1; off < 64; off <<= 1) {
        int u = __shfl_up(inc, off);
        if (lane >= off) inc += u;
    }
    if (lane == 63) wtot[w] = inc;
    __syncthreads();
    int woff = 0;
    for (int k = 0; k < w; ++k) woff += wtot[k];
    int excl = woff + inc - s;
    hoff[i0] = excl; hoff[i0 + 1] = excl + v0;
    hcur[i0] = excl; hcur[i0 + 1] = excl + v0;
    // reserve global space per bucket
    if (i0 < nbk)     gbase[i0]     = atomicAdd(&bcnt[i0],     v0);
    if (i0 + 1 < nbk) gbase[i0 + 1] = atomicAdd(&bcnt[i0 + 1], v1);
    __syncthreads();
#pragma unroll
    for (int i = 0; i < 8; ++i) {
        if (bb[i] >= 0) {
            int r = atomicAdd(&hcur[bb[i]], 1);
            stage[r] = make_int2(src[i], dst[i]);
        }
    }
    __syncthreads();
    int tot = wtot[0] + wtot[1] + wtot[2] + wtot[3];
    for (int t = threadIdx.x; t < tot; t += TPB) {
        int2 p = stage[t];
        int b = p.y >> RSH;
        int gpos = gbase[b] + (t - hoff[b]);
        if (gpos < BCAP) pairs[(size_t)b * BCAP + gpos] = p;   // coalesced runs
    }
}

// ===== tiny scan: bstart[b] = prefix of clamped bcnt; also writes rowptr[N] ====

__global__ void __launch_bounds__(TPB)
bstart_kernel(const int* __restrict__ bcnt, int* __restrict__ bstart,
              int* __restrict__ rowptr, int nbk, int N) {
    __shared__ int wtot[4];
    int i0 = threadIdx.x * 2;
    int v0 = (i0 < nbk) ? min(bcnt[i0], BCAP) : 0;
    int v1 = (i0 + 1 < nbk) ? min(bcnt[i0 + 1], BCAP) : 0;
    int s = v0 + v1;
    int lane = threadIdx.x & 63, w = threadIdx.x >> 6;
    int inc = s;
    for (int off = 1; off < 64; off <<= 1) {
        int u = __shfl_up(inc, off);
        if (lane >= off) inc += u;
    }
    if (lane == 63) wtot[w] = inc;
    __syncthreads();
    int woff = 0;
    for (int k = 0; k < w; ++k) woff += wtot[k];
    int excl = woff + inc - s;
    if (i0 <= nbk)     bstart[i0]     = excl;
    if (i0 + 1 <= nbk) bstart[i0 + 1] = excl + v0;
    if (i0 == nbk)     rowptr[N] = excl;
    if (i0 + 1 == nbk) rowptr[N] = excl + v0;
}

// ===== Phase B: per-bucket counting sort in LDS -> rowptr, dinv, coalesced csr =====
// One block per 256-dst bucket: 391 blocks cover the machine.

__global__ void __launch_bounds__(TPB)
fill3_kernel(const int2* __restrict__ pairs, const int* __restrict__ bcnt,
             const int* __restrict__ bstart, int* __restrict__ rowptr,
             float* __restrict__ dinv, int* __restrict__ csr, int N) {
    __shared__ int h[256];
    __shared__ int wtot[4];
    __shared__ int sbuf[BCAP];
    int b = blockIdx.x;
    int sz = min(bcnt[b], BCAP);
    int base = b << RSH;
    int gbase = bstart[b];
    const int2* pb = pairs + (size_t)b * BCAP;

    h[threadIdx.x] = 0;
    __syncthreads();
    for (int t = threadIdx.x; t < sz; t += TPB)
        atomicAdd(&h[pb[t].y - base], 1);
    __syncthreads();
    int v = h[threadIdx.x];                       // this thread's bin count
    int lane = threadIdx.x & 63, w = threadIdx.x >> 6;
    int inc = v;
    for (int off = 1; off < 64; off <<= 1) {
        int u = __shfl_up(inc, off);
        if (lane >= off) inc += u;
    }
    if (lane == 63) wtot[w] = inc;
    __syncthreads();
    int woff = 0;
    for (int k = 0; k < w; ++k) woff += wtot[k];
    int excl = woff + inc - v;
    h[threadIdx.x] = excl;                        // becomes running cursor
    int idx = base + threadIdx.x;
    if (idx < N) {
        rowptr[idx] = gbase + excl;
        dinv[idx] = rsqrtf((float)v + 1.0f);
    }
    __syncthreads();
    for (int t = threadIdx.x; t < sz; t += TPB) {
        int2 p = pb[t];
        int r = atomicAdd(&h[p.y - base], 1);
        sbuf[r] = p.x;
    }
    __syncthreads();
    for (int t = threadIdx.x; t < sz; t += TPB)
        csr[gbase + t] = sbuf[t];
}

// ========== fp16 helpers ==========

__device__ inline unsigned pack2(float a, float b) {
    __half2 h = __floats2half2_rn(a, b);
    return *reinterpret_cast<unsigned*>(&h);
}
__device__ inline float2 h2f(unsigned u) {
    __half2 h = *reinterpret_cast<__half2*>(&u);
    return __half22float2(h);
}

// ========== first-layer dense linear (f32 row-major out) ==========

template<int DIN, int ISTR, int DOUT, int OSTR, bool RELU>
__global__ void __launch_bounds__(TPB)
linear_kernel(const float* __restrict__ x, const float* __restrict__ W,
              const float* __restrict__ b, float* __restrict__ y, int n) {
    __shared__ float sW[DIN * DOUT];
    __shared__ float sb[DOUT];
    for (int i = threadIdx.x; i < DIN * DOUT; i += blockDim.x) sW[i] = W[i];
    for (int i = threadIdx.x; i < DOUT; i += blockDim.x) sb[i] = b[i];
    __syncthreads();
    int row = blockIdx.x * blockDim.x + threadIdx.x;
    if (row >= n) return;
    float acc[DOUT];
#pragma unroll
    for (int j = 0; j < DOUT; ++j) acc[j] = sb[j];
    const float* xr = x + (size_t)row * ISTR;
    if constexpr (DIN % 4 == 0) {
        const float4* xr4 = (const float4*)xr;
#pragma unroll
        for (int k4 = 0; k4 < DIN / 4; ++k4) {
            float4 xv = xr4[k4];
#pragma unroll
            for (int j = 0; j < DOUT; ++j) acc[j] = fmaf(xv.x, sW[(k4 * 4 + 0) * DOUT + j], acc[j]);
#pragma unroll
            for (int j = 0; j < DOUT; ++j) acc[j] = fmaf(xv.y, sW[(k4 * 4 + 1) * DOUT + j], acc[j]);
#pragma unroll
            for (int j = 0; j < DOUT; ++j) acc[j] = fmaf(xv.z, sW[(k4 * 4 + 2) * DOUT + j], acc[j]);
#pragma unroll
            for (int j = 0; j < DOUT; ++j) acc[j] = fmaf(xv.w, sW[(k4 * 4 + 3) * DOUT + j], acc[j]);
        }
    } else {
#pragma unroll
        for (int k = 0; k < DIN; ++k) {
            float xv = xr[k];
#pragma unroll
            for (int j = 0; j < DOUT; ++j) acc[j] = fmaf(xv, sW[k * DOUT + j], acc[j]);
        }
    }
    float* yr = y + (size_t)row * OSTR;
#pragma unroll
    for (int j = 0; j < DOUT; ++j) yr[j] = RELU ? fmaxf(acc[j], 0.0f) : acc[j];
}

// ========== conv linear: xw_h[row] = fp16( dinv[row] * (x @ W) ), rows padded to P ==========
// DIN fixed at 32 (f32, stride 32). Output row = P halves = P/8 uint4.

template<int DOUT, int P>
__global__ void __launch_bounds__(TPB)
linear_h_kernel(const float* __restrict__ x, const float* __restrict__ W,
                const float* __restrict__ dinv, uint4* __restrict__ xw, int n) {
    __shared__ float sW[32 * DOUT];
    for (int i = threadIdx.x; i < 32 * DOUT; i += blockDim.x) sW[i] = W[i];
    __syncthreads();
    int row = blockIdx.x * blockDim.x + threadIdx.x;
    if (row >= n) return;
    float acc[DOUT];
#pragma unroll
    for (int j = 0; j < DOUT; ++j) acc[j] = 0.0f;
    const float4* xr4 = (const float4*)(x + (size_t)row * 32);
#pragma unroll
    for (int k4 = 0; k4 < 8; ++k4) {
        float4 xv = xr4[k4];
#pragma unroll
        for (int j = 0; j < DOUT; ++j) acc[j] = fmaf(xv.x, sW[(k4 * 4 + 0) * DOUT + j], acc[j]);
#pragma unroll
        for (int j = 0; j < DOUT; ++j) acc[j] = fmaf(xv.y, sW[(k4 * 4 + 1) * DOUT + j], acc[j]);
#pragma unroll
        for (int j = 0; j < DOUT; ++j) acc[j] = fmaf(xv.z, sW[(k4 * 4 + 2) * DOUT + j], acc[j]);
#pragma unroll
        for (int j = 0; j < DOUT; ++j) acc[j] = fmaf(xv.w, sW[(k4 * 4 + 3) * DOUT + j], acc[j]);
    }
    float sc = dinv[row];
    constexpr int C = P / 8;
    uint4* orow = xw + (size_t)row * C;
#pragma unroll
    for (int c = 0; c < C; ++c) {
        float v[8];
#pragma unroll
        for (int j = 0; j < 8; ++j) {
            int d = c * 8 + j;
            v[j] = (d < DOUT) ? sc * acc[d] : 0.0f;
        }
        uint4 u;
        u.x = pack2(v[0], v[1]); u.y = pack2(v[2], v[3]);
        u.z = pack2(v[4], v[5]); u.w = pack2(v[6], v[7]);
        orow[c] = u;
    }
}

// ========== fp16 GCN gather: TPR adjacent lanes read each 16*TPR-byte row coalesced ==========
// y[v,:] = [relu]( dinv[v] * ( xw_h[v,:] + sum_in xw_h[src,:] ) + b ), f32 out stride OSTR

template<int TPR, int OSTR, int DOUT, bool RELU>
__global__ void __launch_bounds__(TPB)
gather_h_kernel(const int* __restrict__ rowptr, const int* __restrict__ csr,
                const uint4* __restrict__ xw, const float* __restrict__ dinv,
                const float* __restrict__ bias, float* __restrict__ y, int n) {
    unsigned tid = blockIdx.x * blockDim.x + threadIdx.x;
    unsigned total = (unsigned)n * (unsigned)TPR;
    if (tid >= total) return;
    unsigned v = tid / TPR;             // compile-time TPR -> magic mul
    unsigned q = tid - v * TPR;
    const uint4* col = xw + q;
    uint4 u = col[(size_t)v * TPR];     // self-loop term
    float2 a0 = h2f(u.x), a1 = h2f(u.y), a2 = h2f(u.z), a3 = h2f(u.w);
    int k = rowptr[v], end = rowptr[v + 1];
    if (k < end) {
        int src = csr[k];
        for (++k; k < end; ++k) {
            int ns = csr[k];            // prefetch next index
            uint4 t = col[(size_t)src * TPR];
            float2 b0 = h2f(t.x), b1 = h2f(t.y), b2 = h2f(t.z), b3 = h2f(t.w);
            a0.x += b0.x; a0.y += b0.y; a1.x += b1.x; a1.y += b1.y;
            a2.x += b2.x; a2.y += b2.y; a3.x += b3.x; a3.y += b3.y;
            src = ns;
        }
        uint4 t = col[(size_t)src * TPR];
        float2 b0 = h2f(t.x), b1 = h2f(t.y), b2 = h2f(t.z), b3 = h2f(t.w);
        a0.x += b0.x; a0.y += b0.y; a1.x += b1.x; a1.y += b1.y;
        a2.x += b2.x; a2.y += b2.y; a3.x += b3.x; a3.y += b3.y;
    }
    float di = dinv[v];
    int d0 = (int)q * 8;
    float r[8] = {a0.x, a0.y, a1.x, a1.y, a2.x, a2.y, a3.x, a3.y};
#pragma unroll
    for (int j = 0; j < 8; ++j) {
        float bj = (d0 + j < DOUT) ? bias[d0 + j] : 0.0f;
        r[j] = fmaf(di, r[j], bj);
        if (RELU) r[j] = fmaxf(r[j], 0.0f);
    }
    float* yr = y + (size_t)v * OSTR + d0;
    if (d0 + 4 <= OSTR) *(float4*)yr = make_float4(r[0], r[1], r[2], r[3]);
    if (d0 + 8 <= OSTR) *(float4*)(yr + 4) = make_float4(r[4], r[5], r[6], r[7]);
}

// ========== head (xf stride 36, xs stride 12) ==========

__global__ void __launch_bounds__(TPB)
head_kernel(const float* __restrict__ xf, const float* __restrict__ xs,
            const float* __restrict__ W1, const float* __restrict__ b1,
            const float* __restrict__ W2, const float* __restrict__ b2,
            float* __restrict__ out, int n) {
    __shared__ float sW1[44 * 33];
    __shared__ float sW2[33 * 30];
    __shared__ float sb1[33];
    __shared__ float sb2[30];
    for (int i = threadIdx.x; i < 44 * 33; i += blockDim.x) sW1[i] = W1[i];
    for (int i = threadIdx.x; i < 33 * 30; i += blockDim.x) sW2[i] = W2[i];
    for (int i = threadIdx.x; i < 33; i += blockDim.x) sb1[i] = b1[i];
    for (int i = threadIdx.x; i < 30; i += blockDim.x) sb2[i] = b2[i];
    __syncthreads();
    int row = blockIdx.x * blockDim.x + threadIdx.x;
    if (row >= n) return;
    float xv[44];
    const float* xfr = xf + (size_t)row * 36;
    const float* xsr = xs + (size_t)row * 12;
#pragma unroll
    for (int k = 0; k < 33; ++k) xv[k] = fmaxf(xfr[k], 0.0f);
#pragma unroll
    for (int k = 0; k < 11; ++k) xv[33 + k] = fmaxf(xsr[k], 0.0f);
    float h[33];
#pragma unroll
    for (int j = 0; j < 33; ++j) h[j] = sb1[j];
#pragma unroll
    for (int k = 0; k < 44; ++k) {
        float xk = xv[k];
#pragma unroll
        for (int j = 0; j < 33; ++j) h[j] = fmaf(xk, sW1[k * 33 + j], h[j]);
    }
    float o[30];
#pragma unroll
    for (int j = 0; j < 30; ++j) o[j] = sb2[j];
#pragma unroll
    for (int k = 0; k < 33; ++k) {
        float hk = fmaxf(h[k], 0.0f);
#pragma unroll
        for (int j = 0; j < 30; ++j) o[j] = fmaf(hk, sW2[k * 30 + j], o[j]);
    }
    float* orow = out + (size_t)row * 30;
#pragma unroll
    for (int j = 0; j < 30; ++j) orow[j] = o[j];
}

// ================= launch =================

extern "C" void kernel_launch(void* const* d_in, const int* in_sizes, int n_in,
                              void* d_out, int out_size, void* d_ws, size_t ws_size,
                              hipStream_t stream) {
    const float* feat  = (const float*)d_in[0];
    const float* spat  = (const float*)d_in[1];
    const int*   ei_f  = (const int*)d_in[2];
    const int*   ei_s  = (const int*)d_in[3];
    const float* W_fc  = (const float*)d_in[4];
    const float* b_fc  = (const float*)d_in[5];
    const float* W_cnn = (const float*)d_in[6];
    const float* b_cnn = (const float*)d_in[7];
    const float* Wf1 = (const float*)d_in[8];
    const float* bf1 = (const float*)d_in[9];
    const float* Wf2 = (const float*)d_in[10];
    const float* bf2 = (const float*)d_in[11];
    const float* Ws1 = (const float*)d_in[12];
    const float* bs1 = (const float*)d_in[13];
    const float* Ws2 = (const float*)d_in[14];
    const float* bs2 = (const float*)d_in[15];
    const float* Wp1 = (const float*)d_in[16];
    const float* bp1 = (const float*)d_in[17];
    const float* Wp2 = (const float*)d_in[18];
    const float* bp2 = (const float*)d_in[19];
    float* out = (float*)d_out;

    const int N = in_sizes[0] / 31;
    const int E = in_sizes[2] / 2;
    const int nbk = (N + 255) >> RSH;            // 256-dst buckets
    const int bgrid = (E + BK_TILE - 1) / BK_TILE;

    // workspace layout (4B elements), ~47MB
    float* R0   = (float*)d_ws;                  // N*36 row-major f32
    float* R1   = R0 + (size_t)N * 36;           // N*32 row-major f32
    float* XWH  = R1 + (size_t)N * 32;           // N*40 halves = N*20 f32 slots
    float* S    = XWH + (size_t)N * 20;          // N*12 (xs2)
    float* dinv = S + (size_t)N * 12;            // N
    int*   rowptr = (int*)(dinv + N);            // N+1
    int*   bcnt   = rowptr + (N + 1);            // NBMAX
    int*   bstart = bcnt + NBMAX;                // NBMAX+1
    int*   csr    = bstart + (NBMAX + 4);        // E
    int2*  pairs  = (int2*)R0;                   // nbk*BCAP int2 = 16MB, overlays R0∪R1

    auto gb = [](long long n) { return (unsigned)((n + TPB - 1) / TPB); };

    // ---------- spat CSR + branch ----------
    hipMemsetAsync(bcnt, 0, sizeof(int) * NBMAX, stream);
    bucket_kernel<<<bgrid, TPB, 0, stream>>>(ei_s, bcnt, pairs, E, nbk);
    bstart_kernel<<<1, TPB, 0, stream>>>(bcnt, bstart, rowptr, nbk, N);
    fill3_kernel<<<nbk, TPB, 0, stream>>>(pairs, bcnt, bstart, rowptr, dinv, csr, N);

    linear_kernel<128, 128, 32, 32, true><<<gb(N), TPB, 0, stream>>>(spat, W_cnn, b_cnn, R0, N);
    linear_h_kernel<32, 32><<<gb(N), TPB, 0, stream>>>(R0, Ws1, dinv, (uint4*)XWH, N);
    gather_h_kernel<4, 32, 32, true><<<gb((long long)N * 4), TPB, 0, stream>>>(rowptr, csr, (const uint4*)XWH, dinv, bs1, R1, N);
    linear_h_kernel<11, 16><<<gb(N), TPB, 0, stream>>>(R1, Ws2, dinv, (uint4*)XWH, N);
    gather_h_kernel<2, 12, 11, false><<<gb((long long)N * 2), TPB, 0, stream>>>(rowptr, csr, (const uint4*)XWH, dinv, bs2, S, N);
    // xs2 -> S (stride 12)

    // ---------- feat CSR + branch (R0,R1 dead during build; S,XWH untouched by pairs) ----------
    hipMemsetAsync(bcnt, 0, sizeof(int) * NBMAX, stream);
    bucket_kernel<<<bgrid, TPB, 0, stream>>>(ei_f, bcnt, pairs, E, nbk);
    bstart_kernel<<<1, TPB, 0, stream>>>(bcnt, bstart, rowptr, nbk, N);
    fill3_kernel<<<nbk, TPB, 0, stream>>>(pairs, bcnt, bstart, rowptr, dinv, csr, N);

    linear_kernel<31, 31, 32, 32, true><<<gb(N), TPB, 0, stream>>>(feat, W_fc, b_fc, R0, N);
    linear_h_kernel<32, 32><<<gb(N), TPB, 0, stream>>>(R0, Wf1, dinv, (uint4*)XWH, N);
    gather_h_kernel<4, 32, 32, true><<<gb((long long)N * 4), TPB, 0, stream>>>(rowptr, csr, (const uint4*)XWH, dinv, bf1, R1, N);
    linear_h_kernel<33, 40><<<gb(N), TPB, 0, stream>>>(R1, Wf2, dinv, (uint4*)XWH, N);
    gather_h_kernel<5, 36, 33, false><<<gb((long long)N * 5), TPB, 0, stream>>>(rowptr, csr, (const uint4*)XWH, dinv, bf2, R0, N);
    // xf2 -> R0 (stride 36)

    // ---------- head ----------
    head_kernel<<<gb(N), TPB, 0, stream>>>(R0, S, Wp1, bp1, Wp2, bp2, out, N);
}